// Round 1
// baseline (30.012 us; speedup 1.0000x reference)
//
#include <hip/hip_runtime.h>
#include <hip/hip_bf16.h>

// SpreadGNN on MI355X (gfx950).
// Key insight: fully-connected per-graph edges => segment mean == per-graph mean.
//   h+ = relu( Wl * mean_g(h) + b + Wr * h ), x3 layers, then out = Wp * mean_g(h3) + bp.
// One wave == one graph (32 nodes). Activations kept f-major G[f][node]:
//   MFMA: D[f][node] = A(=W, M=f_out, K) x B(=G, K, N=node).
// All cross-lane traffic is intra-wave (per-wave LDS scratch, no __syncthreads).
// Weights pre-packed to bf16 A-fragment layout in d_ws by gnn_prep (104 KB).

typedef float f32x4 __attribute__((ext_vector_type(4)));
typedef __bf16 bf16x8 __attribute__((ext_vector_type(8)));

__device__ __forceinline__ f32x4 MFMA(bf16x8 a, bf16x8 b, f32x4 c) {
  return __builtin_amdgcn_mfma_f32_16x16x32_bf16(a, b, c, 0, 0, 0);
}

__device__ __forceinline__ unsigned short bfbits(float v) {
  __hip_bfloat16 t = __float2bfloat16(v);   // RNE
  return __builtin_bit_cast(unsigned short, t);
}

__device__ __forceinline__ bf16x8 pack8(f32x4 lo, f32x4 hi) {
  union { bf16x8 v; unsigned short u[8]; } t;
  t.u[0] = bfbits(lo[0]); t.u[1] = bfbits(lo[1]);
  t.u[2] = bfbits(lo[2]); t.u[3] = bfbits(lo[3]);
  t.u[4] = bfbits(hi[0]); t.u[5] = bfbits(hi[1]);
  t.u[6] = bfbits(hi[2]); t.u[7] = bfbits(hi[3]);
  return t.v;
}

// ---- weight prep: pack W[f][k] (f32) -> bf16 A-fragments -------------------
// pack element index: ((ft*KS + ks)*64 + lane)*8 + j
//   f = ft*16 + (lane&15),  k = ks*32 + (lane>>4)*8 + j,  0 if k >= Kreal
// segments (elements): A1r[0,2048) A1l[2048,4096) A2r[4096,12288)
//   A2l[12288,20480) A3r[20480,36864) A3l[36864,53248)
__global__ __launch_bounds__(256) void gnn_prep(
    const float* __restrict__ W1l, const float* __restrict__ W1r,
    const float* __restrict__ W2l, const float* __restrict__ W2r,
    const float* __restrict__ W3l, const float* __restrict__ W3r,
    unsigned short* __restrict__ wpack)
{
  int e = blockIdx.x * 256 + threadIdx.x;
  if (e >= 53248) return;
  const float* src; int Kreal, KS, eloc;
  if      (e < 2048)  { src = W1r; Kreal = 5;   KS = 1; eloc = e; }
  else if (e < 4096)  { src = W1l; Kreal = 5;   KS = 1; eloc = e - 2048; }
  else if (e < 12288) { src = W2r; Kreal = 64;  KS = 2; eloc = e - 4096; }
  else if (e < 20480) { src = W2l; Kreal = 64;  KS = 2; eloc = e - 12288; }
  else if (e < 36864) { src = W3r; Kreal = 128; KS = 4; eloc = e - 20480; }
  else                { src = W3l; Kreal = 128; KS = 4; eloc = e - 36864; }
  int j = eloc & 7, lane = (eloc >> 3) & 63, rest = eloc >> 9;
  int ks = rest % KS, ft = rest / KS;
  int f = ft * 16 + (lane & 15);
  int k = ks * 32 + (lane >> 4) * 8 + j;
  float v = (k < Kreal) ? src[f * Kreal + k] : 0.f;
  wpack[e] = bfbits(v);
}

// ---- fused GNN: 1 wave = 1 graph ------------------------------------------
__global__ __launch_bounds__(256) void gnn_fused(
    const float* __restrict__ obs,
    const float* __restrict__ b1, const float* __restrict__ b2,
    const float* __restrict__ b3,
    const float* __restrict__ Wp, const float* __restrict__ bp,
    const unsigned short* __restrict__ wpack,
    float* __restrict__ out)
{
  // per-wave scratch: rb = [node 0..31][f-half 0..63 +4 pad] f32 (transpose+mean)
  //                   mb = mean vector (128 f32)
  __shared__ float rb_all[4][32 * 68];
  __shared__ float mb_all[4][128];

  const int tid  = threadIdx.x;
  const int wid  = tid >> 6;
  const int lane = tid & 63;
  const int g    = lane >> 4;   // 4 groups of 16
  const int c    = lane & 15;   // node-col within tile / f-quad id
  float* rb = &rb_all[wid][0];
  float* mb = &mb_all[wid][0];
  const int graph = blockIdx.x * 4 + wid;
  const float* xg = obs + graph * 160;

  const unsigned short* A1r = wpack;
  const unsigned short* A1l = wpack + 2048;
  const unsigned short* A2r = wpack + 4096;
  const unsigned short* A2l = wpack + 12288;
  const unsigned short* A3r = wpack + 20480;
  const unsigned short* A3l = wpack + 36864;

  const f32x4 Z4 = {0.f, 0.f, 0.f, 0.f};

  // ---------------- Layer 1 (5 -> 64) ----------------
  float x0[5], x1[5];
#pragma unroll
  for (int j = 0; j < 5; ++j) { x0[j] = xg[c * 5 + j]; x1[j] = xg[80 + c * 5 + j]; }
  float m0[5];
#pragma unroll
  for (int j = 0; j < 5; ++j) {
    float s = x0[j] + x1[j];
    s += __shfl_xor(s, 1, 64); s += __shfl_xor(s, 2, 64);
    s += __shfl_xor(s, 4, 64); s += __shfl_xor(s, 8, 64);
    m0[j] = s * 0.03125f;
  }
  bf16x8 Bn1[2], Bg1;
  {
    f32x4 a0 = {x0[0], x0[1], x0[2], x0[3]}, a1 = {x0[4], 0.f, 0.f, 0.f};
    f32x4 n0 = {x1[0], x1[1], x1[2], x1[3]}, n1 = {x1[4], 0.f, 0.f, 0.f};
    f32x4 g0 = {m0[0], m0[1], m0[2], m0[3]}, g1 = {m0[4], 0.f, 0.f, 0.f};
    if (g != 0) { a0 = Z4; a1 = Z4; n0 = Z4; n1 = Z4; g0 = Z4; g1 = Z4; }
    Bn1[0] = pack8(a0, a1); Bn1[1] = pack8(n0, n1); Bg1 = pack8(g0, g1);
  }

  f32x4 acc[2][8];
#pragma unroll
  for (int ft = 0; ft < 4; ++ft) {
    f32x4 bias = *(const f32x4*)(b1 + ft * 16 + 4 * g);
    acc[0][ft] = bias; acc[1][ft] = bias;
    bf16x8 ar = *(const bf16x8*)(A1r + (ft * 64 + lane) * 8);
    bf16x8 al = *(const bf16x8*)(A1l + (ft * 64 + lane) * 8);
    acc[0][ft] = MFMA(ar, Bn1[0], acc[0][ft]);
    acc[1][ft] = MFMA(ar, Bn1[1], acc[1][ft]);
    acc[0][ft] = MFMA(al, Bg1, acc[0][ft]);
    acc[1][ft] = MFMA(al, Bg1, acc[1][ft]);
  }
#pragma unroll
  for (int ct = 0; ct < 2; ++ct)
#pragma unroll
    for (int ft = 0; ft < 4; ++ft)
#pragma unroll
      for (int i = 0; i < 4; ++i)
        acc[ct][ft][i] = fmaxf(acc[ct][ft][i], 0.f);

  // L1 epilogue: transpose via rb, mean -> mb[0..63], build next frags
  bf16x8 Bn2[2][2], Bg2[2];
  {
#pragma unroll
    for (int ct = 0; ct < 2; ++ct)
#pragma unroll
      for (int ft = 0; ft < 4; ++ft)
        *(f32x4*)(rb + (ct * 16 + c) * 68 + ft * 16 + 4 * g) = acc[ct][ft];
    f32x4 sum = Z4;
#pragma unroll
    for (int cc = 0; cc < 8; ++cc)
      sum += *(const f32x4*)(rb + (g * 8 + cc) * 68 + c * 4);
#pragma unroll
    for (int i = 0; i < 4; ++i) {
      float v = sum[i];
      v += __shfl_xor(v, 16, 64); v += __shfl_xor(v, 32, 64);
      sum[i] = v * 0.03125f;
    }
    if (g == 0) *(f32x4*)(mb + c * 4) = sum;
#pragma unroll
    for (int ct = 0; ct < 2; ++ct)
#pragma unroll
      for (int ks = 0; ks < 2; ++ks) {
        f32x4 lo = *(const f32x4*)(rb + (ct * 16 + c) * 68 + ks * 32 + 8 * g);
        f32x4 hi = *(const f32x4*)(rb + (ct * 16 + c) * 68 + ks * 32 + 8 * g + 4);
        Bn2[ct][ks] = pack8(lo, hi);
      }
#pragma unroll
    for (int ks = 0; ks < 2; ++ks) {
      f32x4 lo = *(const f32x4*)(mb + ks * 32 + 8 * g);
      f32x4 hi = *(const f32x4*)(mb + ks * 32 + 8 * g + 4);
      Bg2[ks] = pack8(lo, hi);
    }
  }

  // ---------------- Layer 2 (64 -> 128) ----------------
#pragma unroll
  for (int ft = 0; ft < 8; ++ft) {
    f32x4 bias = *(const f32x4*)(b2 + ft * 16 + 4 * g);
    acc[0][ft] = bias; acc[1][ft] = bias;
#pragma unroll
    for (int ks = 0; ks < 2; ++ks) {
      bf16x8 ar = *(const bf16x8*)(A2r + ((ft * 2 + ks) * 64 + lane) * 8);
      bf16x8 al = *(const bf16x8*)(A2l + ((ft * 2 + ks) * 64 + lane) * 8);
      acc[0][ft] = MFMA(ar, Bn2[0][ks], acc[0][ft]);
      acc[1][ft] = MFMA(ar, Bn2[1][ks], acc[1][ft]);
      acc[0][ft] = MFMA(al, Bg2[ks], acc[0][ft]);
      acc[1][ft] = MFMA(al, Bg2[ks], acc[1][ft]);
    }
  }
#pragma unroll
  for (int ct = 0; ct < 2; ++ct)
#pragma unroll
    for (int ft = 0; ft < 8; ++ft)
#pragma unroll
      for (int i = 0; i < 4; ++i)
        acc[ct][ft][i] = fmaxf(acc[ct][ft][i], 0.f);

  // L2 epilogue: two f-halves through rb; mean -> mb[0..127]
  bf16x8 Bn3[2][4], Bg3[4];
#pragma unroll
  for (int h = 0; h < 2; ++h) {
#pragma unroll
    for (int ct = 0; ct < 2; ++ct)
#pragma unroll
      for (int q = 0; q < 4; ++q)
        *(f32x4*)(rb + (ct * 16 + c) * 68 + q * 16 + 4 * g) = acc[ct][4 * h + q];
    f32x4 sum = Z4;
#pragma unroll
    for (int cc = 0; cc < 8; ++cc)
      sum += *(const f32x4*)(rb + (g * 8 + cc) * 68 + c * 4);
#pragma unroll
    for (int i = 0; i < 4; ++i) {
      float v = sum[i];
      v += __shfl_xor(v, 16, 64); v += __shfl_xor(v, 32, 64);
      sum[i] = v * 0.03125f;
    }
    if (g == 0) *(f32x4*)(mb + 64 * h + c * 4) = sum;
#pragma unroll
    for (int ct = 0; ct < 2; ++ct)
#pragma unroll
      for (int k2 = 0; k2 < 2; ++k2) {
        f32x4 lo = *(const f32x4*)(rb + (ct * 16 + c) * 68 + k2 * 32 + 8 * g);
        f32x4 hi = *(const f32x4*)(rb + (ct * 16 + c) * 68 + k2 * 32 + 8 * g + 4);
        Bn3[ct][2 * h + k2] = pack8(lo, hi);
      }
  }
#pragma unroll
  for (int ks = 0; ks < 4; ++ks) {
    f32x4 lo = *(const f32x4*)(mb + ks * 32 + 8 * g);
    f32x4 hi = *(const f32x4*)(mb + ks * 32 + 8 * g + 4);
    Bg3[ks] = pack8(lo, hi);
  }

  // ---------------- Layer 3 (128 -> 128) ----------------
#pragma unroll
  for (int ft = 0; ft < 8; ++ft) {
    f32x4 bias = *(const f32x4*)(b3 + ft * 16 + 4 * g);
    acc[0][ft] = bias; acc[1][ft] = bias;
#pragma unroll
    for (int ks = 0; ks < 4; ++ks) {
      bf16x8 ar = *(const bf16x8*)(A3r + ((ft * 4 + ks) * 64 + lane) * 8);
      bf16x8 al = *(const bf16x8*)(A3l + ((ft * 4 + ks) * 64 + lane) * 8);
      acc[0][ft] = MFMA(ar, Bn3[0][ks], acc[0][ft]);
      acc[1][ft] = MFMA(ar, Bn3[1][ks], acc[1][ft]);
      acc[0][ft] = MFMA(al, Bg3[ks], acc[0][ft]);
      acc[1][ft] = MFMA(al, Bg3[ks], acc[1][ft]);
    }
  }
#pragma unroll
  for (int ct = 0; ct < 2; ++ct)
#pragma unroll
    for (int ft = 0; ft < 8; ++ft)
#pragma unroll
      for (int i = 0; i < 4; ++i)
        acc[ct][ft][i] = fmaxf(acc[ct][ft][i], 0.f);

  // L3 epilogue: pooled = mean(relu(h3)) -> mb (f32, never touches bf16)
#pragma unroll
  for (int h = 0; h < 2; ++h) {
#pragma unroll
    for (int ct = 0; ct < 2; ++ct)
#pragma unroll
      for (int q = 0; q < 4; ++q)
        *(f32x4*)(rb + (ct * 16 + c) * 68 + q * 16 + 4 * g) = acc[ct][4 * h + q];
    f32x4 sum = Z4;
#pragma unroll
    for (int cc = 0; cc < 8; ++cc)
      sum += *(const f32x4*)(rb + (g * 8 + cc) * 68 + c * 4);
#pragma unroll
    for (int i = 0; i < 4; ++i) {
      float v = sum[i];
      v += __shfl_xor(v, 16, 64); v += __shfl_xor(v, 32, 64);
      sum[i] = v * 0.03125f;
    }
    if (g == 0) *(f32x4*)(mb + 64 * h + c * 4) = sum;
  }

  // ---------------- head: out = Wp * pooled + bp (f32) ----------------
  float p0 = mb[lane], p1 = mb[64 + lane];
  float po[5];
#pragma unroll
  for (int o = 0; o < 5; ++o)
    po[o] = p0 * Wp[o * 128 + lane] + p1 * Wp[o * 128 + 64 + lane];
#pragma unroll
  for (int o = 0; o < 5; ++o) {
    float v = po[o];
    v += __shfl_xor(v, 1, 64);  v += __shfl_xor(v, 2, 64);
    v += __shfl_xor(v, 4, 64);  v += __shfl_xor(v, 8, 64);
    v += __shfl_xor(v, 16, 64); v += __shfl_xor(v, 32, 64);
    po[o] = v;
  }
  if (lane == 0) {
#pragma unroll
    for (int o = 0; o < 5; ++o) out[graph * 5 + o] = po[o] + bp[o];
  }
}

extern "C" void kernel_launch(void* const* d_in, const int* in_sizes, int n_in,
                              void* d_out, int out_size, void* d_ws, size_t ws_size,
                              hipStream_t stream)
{
  const float* obs = (const float*)d_in[0];
  // d_in[1]=src, d_in[2]=dst: fully-connected per-graph -> segment mean; unused.
  const float* W1l = (const float*)d_in[3];
  const float* b1  = (const float*)d_in[4];
  const float* W1r = (const float*)d_in[5];
  const float* W2l = (const float*)d_in[6];
  const float* b2  = (const float*)d_in[7];
  const float* W2r = (const float*)d_in[8];
  const float* W3l = (const float*)d_in[9];
  const float* b3  = (const float*)d_in[10];
  const float* W3r = (const float*)d_in[11];
  const float* Wp  = (const float*)d_in[12];
  const float* bp  = (const float*)d_in[13];
  unsigned short* wpack = (unsigned short*)d_ws;   // needs 104 KB of d_ws
  float* out = (float*)d_out;

  gnn_prep<<<208, 256, 0, stream>>>(W1l, W1r, W2l, W2r, W3l, W3r, wpack);
  gnn_fused<<<512, 256, 0, stream>>>(obs, b1, b2, b3, Wp, bp, wpack, out);
}

// Round 2
// 22.004 us; speedup vs baseline: 1.3639x; 1.3639x over previous
//
#include <hip/hip_runtime.h>
#include <hip/hip_bf16.h>

// SpreadGNN on MI355X (gfx950).
// Fully-connected per-graph edges => segment mean == per-graph mean:
//   h+ = relu( Wl * mean_g(h) + b + Wr * h ), x3, then out = Wp * mean_g(h3) + bp.
// One wave == one graph (32 nodes), activations f-major G[f][node].
// Round 1: 8-wave blocks; layer-3 weights (A3, 64KB) staged to LDS once per
// block via global_load_lds (issued at kernel start, barrier before L3) —
// removes the dominant per-wave L2 fragment traffic/latency.

typedef float f32x4 __attribute__((ext_vector_type(4)));
typedef __bf16 bf16x8 __attribute__((ext_vector_type(8)));

__device__ __forceinline__ f32x4 MFMA(bf16x8 a, bf16x8 b, f32x4 c) {
  return __builtin_amdgcn_mfma_f32_16x16x32_bf16(a, b, c, 0, 0, 0);
}

__device__ __forceinline__ unsigned short bfbits(float v) {
  __hip_bfloat16 t = __float2bfloat16(v);   // RNE
  return __builtin_bit_cast(unsigned short, t);
}

__device__ __forceinline__ bf16x8 pack8(f32x4 lo, f32x4 hi) {
  union { bf16x8 v; unsigned short u[8]; } t;
  t.u[0] = bfbits(lo[0]); t.u[1] = bfbits(lo[1]);
  t.u[2] = bfbits(lo[2]); t.u[3] = bfbits(lo[3]);
  t.u[4] = bfbits(hi[0]); t.u[5] = bfbits(hi[1]);
  t.u[6] = bfbits(hi[2]); t.u[7] = bfbits(hi[3]);
  return t.v;
}

// ---- weight prep: pack W[f][k] (f32) -> bf16 A-fragments -------------------
// pack element index: ((ft*KS + ks)*64 + lane)*8 + j
//   f = ft*16 + (lane&15),  k = ks*32 + (lane>>4)*8 + j,  0 if k >= Kreal
// segments (elements): A1r[0,2048) A1l[2048,4096) A2r[4096,12288)
//   A2l[12288,20480) A3r[20480,36864) A3l[36864,53248)
__global__ __launch_bounds__(256) void gnn_prep(
    const float* __restrict__ W1l, const float* __restrict__ W1r,
    const float* __restrict__ W2l, const float* __restrict__ W2r,
    const float* __restrict__ W3l, const float* __restrict__ W3r,
    unsigned short* __restrict__ wpack)
{
  int e = blockIdx.x * 256 + threadIdx.x;
  if (e >= 53248) return;
  const float* src; int Kreal, KS, eloc;
  if      (e < 2048)  { src = W1r; Kreal = 5;   KS = 1; eloc = e; }
  else if (e < 4096)  { src = W1l; Kreal = 5;   KS = 1; eloc = e - 2048; }
  else if (e < 12288) { src = W2r; Kreal = 64;  KS = 2; eloc = e - 4096; }
  else if (e < 20480) { src = W2l; Kreal = 64;  KS = 2; eloc = e - 12288; }
  else if (e < 36864) { src = W3r; Kreal = 128; KS = 4; eloc = e - 20480; }
  else                { src = W3l; Kreal = 128; KS = 4; eloc = e - 36864; }
  int j = eloc & 7, lane = (eloc >> 3) & 63, rest = eloc >> 9;
  int ks = rest % KS, ft = rest / KS;
  int f = ft * 16 + (lane & 15);
  int k = ks * 32 + (lane >> 4) * 8 + j;
  float v = (k < Kreal) ? src[f * Kreal + k] : 0.f;
  wpack[e] = bfbits(v);
}

// ---- fused GNN: 1 wave = 1 graph, 8 waves/block, A3 in LDS -----------------
__global__ __launch_bounds__(512) void gnn_fused(
    const float* __restrict__ obs,
    const float* __restrict__ b1, const float* __restrict__ b2,
    const float* __restrict__ b3,
    const float* __restrict__ Wp, const float* __restrict__ bp,
    const unsigned short* __restrict__ wpack,
    float* __restrict__ out)
{
  // LDS: A3 weights (64KB) + per-wave transpose scratch rb + mean buffer mb
  __shared__ unsigned short smA3[32768];          // A3r [0,16384) A3l [16384,32768)
  __shared__ float rb_all[8][32 * 68];
  __shared__ float mb_all[8][128];

  const int tid  = threadIdx.x;
  const int wid  = tid >> 6;     // 0..7
  const int lane = tid & 63;
  const int g    = lane >> 4;    // 4 groups of 16
  const int c    = lane & 15;    // node-col within tile / f-quad id
  float* rb = &rb_all[wid][0];
  float* mb = &mb_all[wid][0];
  const int graph = blockIdx.x * 8 + wid;
  const float* xg = obs + graph * 160;

  const unsigned short* A1r = wpack;
  const unsigned short* A1l = wpack + 2048;
  const unsigned short* A2r = wpack + 4096;
  const unsigned short* A2l = wpack + 12288;

  // ---- issue A3 staging first: 64 chunks x 1KB, 8 per wave ----
  {
    const unsigned short* gA3 = wpack + 20480;
#pragma unroll
    for (int it = 0; it < 8; ++it) {
      const int chunk = it * 8 + wid;   // wave-uniform
      const void* gsrc = (const void*)((const char*)(gA3 + chunk * 512) + lane * 16);
      __builtin_amdgcn_global_load_lds(
          (const __attribute__((address_space(1))) unsigned int*)gsrc,
          (__attribute__((address_space(3))) unsigned int*)&smA3[chunk * 512],
          16, 0, 0);
    }
  }

  const f32x4 Z4 = {0.f, 0.f, 0.f, 0.f};

  // ---------------- Layer 1 (5 -> 64) ----------------
  float x0[5], x1[5];
#pragma unroll
  for (int j = 0; j < 5; ++j) { x0[j] = xg[c * 5 + j]; x1[j] = xg[80 + c * 5 + j]; }
  float m0[5];
#pragma unroll
  for (int j = 0; j < 5; ++j) {
    float s = x0[j] + x1[j];
    s += __shfl_xor(s, 1, 64); s += __shfl_xor(s, 2, 64);
    s += __shfl_xor(s, 4, 64); s += __shfl_xor(s, 8, 64);
    m0[j] = s * 0.03125f;
  }
  bf16x8 Bn1[2], Bg1;
  {
    f32x4 a0 = {x0[0], x0[1], x0[2], x0[3]}, a1 = {x0[4], 0.f, 0.f, 0.f};
    f32x4 n0 = {x1[0], x1[1], x1[2], x1[3]}, n1 = {x1[4], 0.f, 0.f, 0.f};
    f32x4 g0 = {m0[0], m0[1], m0[2], m0[3]}, g1 = {m0[4], 0.f, 0.f, 0.f};
    if (g != 0) { a0 = Z4; a1 = Z4; n0 = Z4; n1 = Z4; g0 = Z4; g1 = Z4; }
    Bn1[0] = pack8(a0, a1); Bn1[1] = pack8(n0, n1); Bg1 = pack8(g0, g1);
  }

  f32x4 acc[2][8];
#pragma unroll
  for (int ft = 0; ft < 4; ++ft) {
    f32x4 bias = *(const f32x4*)(b1 + ft * 16 + 4 * g);
    acc[0][ft] = bias; acc[1][ft] = bias;
    bf16x8 ar = *(const bf16x8*)(A1r + (ft * 64 + lane) * 8);
    bf16x8 al = *(const bf16x8*)(A1l + (ft * 64 + lane) * 8);
    acc[0][ft] = MFMA(ar, Bn1[0], acc[0][ft]);
    acc[1][ft] = MFMA(ar, Bn1[1], acc[1][ft]);
    acc[0][ft] = MFMA(al, Bg1, acc[0][ft]);
    acc[1][ft] = MFMA(al, Bg1, acc[1][ft]);
  }
#pragma unroll
  for (int ct = 0; ct < 2; ++ct)
#pragma unroll
    for (int ft = 0; ft < 4; ++ft)
#pragma unroll
      for (int i = 0; i < 4; ++i)
        acc[ct][ft][i] = fmaxf(acc[ct][ft][i], 0.f);

  // L1 epilogue: transpose via rb, mean -> mb[0..63], build next frags
  bf16x8 Bn2[2][2], Bg2[2];
  {
#pragma unroll
    for (int ct = 0; ct < 2; ++ct)
#pragma unroll
      for (int ft = 0; ft < 4; ++ft)
        *(f32x4*)(rb + (ct * 16 + c) * 68 + ft * 16 + 4 * g) = acc[ct][ft];
    f32x4 sum = Z4;
#pragma unroll
    for (int cc = 0; cc < 8; ++cc)
      sum += *(const f32x4*)(rb + (g * 8 + cc) * 68 + c * 4);
#pragma unroll
    for (int i = 0; i < 4; ++i) {
      float v = sum[i];
      v += __shfl_xor(v, 16, 64); v += __shfl_xor(v, 32, 64);
      sum[i] = v * 0.03125f;
    }
    if (g == 0) *(f32x4*)(mb + c * 4) = sum;
#pragma unroll
    for (int ct = 0; ct < 2; ++ct)
#pragma unroll
      for (int ks = 0; ks < 2; ++ks) {
        f32x4 lo = *(const f32x4*)(rb + (ct * 16 + c) * 68 + ks * 32 + 8 * g);
        f32x4 hi = *(const f32x4*)(rb + (ct * 16 + c) * 68 + ks * 32 + 8 * g + 4);
        Bn2[ct][ks] = pack8(lo, hi);
      }
#pragma unroll
    for (int ks = 0; ks < 2; ++ks) {
      f32x4 lo = *(const f32x4*)(mb + ks * 32 + 8 * g);
      f32x4 hi = *(const f32x4*)(mb + ks * 32 + 8 * g + 4);
      Bg2[ks] = pack8(lo, hi);
    }
  }

  // ---------------- Layer 2 (64 -> 128) ----------------
#pragma unroll
  for (int ft = 0; ft < 8; ++ft) {
    f32x4 bias = *(const f32x4*)(b2 + ft * 16 + 4 * g);
    acc[0][ft] = bias; acc[1][ft] = bias;
#pragma unroll
    for (int ks = 0; ks < 2; ++ks) {
      bf16x8 ar = *(const bf16x8*)(A2r + ((ft * 2 + ks) * 64 + lane) * 8);
      bf16x8 al = *(const bf16x8*)(A2l + ((ft * 2 + ks) * 64 + lane) * 8);
      acc[0][ft] = MFMA(ar, Bn2[0][ks], acc[0][ft]);
      acc[1][ft] = MFMA(ar, Bn2[1][ks], acc[1][ft]);
      acc[0][ft] = MFMA(al, Bg2[ks], acc[0][ft]);
      acc[1][ft] = MFMA(al, Bg2[ks], acc[1][ft]);
    }
  }
#pragma unroll
  for (int ct = 0; ct < 2; ++ct)
#pragma unroll
    for (int ft = 0; ft < 8; ++ft)
#pragma unroll
      for (int i = 0; i < 4; ++i)
        acc[ct][ft][i] = fmaxf(acc[ct][ft][i], 0.f);

  // L2 epilogue: two f-halves through rb; mean -> mb[0..127]
  bf16x8 Bn3[2][4], Bg3[4];
#pragma unroll
  for (int h = 0; h < 2; ++h) {
#pragma unroll
    for (int ct = 0; ct < 2; ++ct)
#pragma unroll
      for (int q = 0; q < 4; ++q)
        *(f32x4*)(rb + (ct * 16 + c) * 68 + q * 16 + 4 * g) = acc[ct][4 * h + q];
    f32x4 sum = Z4;
#pragma unroll
    for (int cc = 0; cc < 8; ++cc)
      sum += *(const f32x4*)(rb + (g * 8 + cc) * 68 + c * 4);
#pragma unroll
    for (int i = 0; i < 4; ++i) {
      float v = sum[i];
      v += __shfl_xor(v, 16, 64); v += __shfl_xor(v, 32, 64);
      sum[i] = v * 0.03125f;
    }
    if (g == 0) *(f32x4*)(mb + 64 * h + c * 4) = sum;
#pragma unroll
    for (int ct = 0; ct < 2; ++ct)
#pragma unroll
      for (int k2 = 0; k2 < 2; ++k2) {
        f32x4 lo = *(const f32x4*)(rb + (ct * 16 + c) * 68 + k2 * 32 + 8 * g);
        f32x4 hi = *(const f32x4*)(rb + (ct * 16 + c) * 68 + k2 * 32 + 8 * g + 4);
        Bn3[ct][2 * h + k2] = pack8(lo, hi);
      }
  }
#pragma unroll
  for (int ks = 0; ks < 4; ++ks) {
    f32x4 lo = *(const f32x4*)(mb + ks * 32 + 8 * g);
    f32x4 hi = *(const f32x4*)(mb + ks * 32 + 8 * g + 4);
    Bg3[ks] = pack8(lo, hi);
  }

  // ---- staged A3 must be resident before L3 fragment reads ----
  asm volatile("s_waitcnt vmcnt(0)" ::: "memory");
  __syncthreads();

  // ---------------- Layer 3 (128 -> 128), weights from LDS ----------------
  const unsigned short* A3r = smA3;           // [0,16384)
  const unsigned short* A3l = smA3 + 16384;   // [16384,32768)
#pragma unroll
  for (int ft = 0; ft < 8; ++ft) {
    f32x4 bias = *(const f32x4*)(b3 + ft * 16 + 4 * g);
    acc[0][ft] = bias; acc[1][ft] = bias;
#pragma unroll
    for (int ks = 0; ks < 4; ++ks) {
      bf16x8 ar = *(const bf16x8*)(A3r + ((ft * 4 + ks) * 64 + lane) * 8);
      bf16x8 al = *(const bf16x8*)(A3l + ((ft * 4 + ks) * 64 + lane) * 8);
      acc[0][ft] = MFMA(ar, Bn3[0][ks], acc[0][ft]);
      acc[1][ft] = MFMA(ar, Bn3[1][ks], acc[1][ft]);
      acc[0][ft] = MFMA(al, Bg3[ks], acc[0][ft]);
      acc[1][ft] = MFMA(al, Bg3[ks], acc[1][ft]);
    }
  }
#pragma unroll
  for (int ct = 0; ct < 2; ++ct)
#pragma unroll
    for (int ft = 0; ft < 8; ++ft)
#pragma unroll
      for (int i = 0; i < 4; ++i)
        acc[ct][ft][i] = fmaxf(acc[ct][ft][i], 0.f);

  // L3 epilogue: pooled = mean(relu(h3)) -> mb (f32, never touches bf16)
#pragma unroll
  for (int h = 0; h < 2; ++h) {
#pragma unroll
    for (int ct = 0; ct < 2; ++ct)
#pragma unroll
      for (int q = 0; q < 4; ++q)
        *(f32x4*)(rb + (ct * 16 + c) * 68 + q * 16 + 4 * g) = acc[ct][4 * h + q];
    f32x4 sum = Z4;
#pragma unroll
    for (int cc = 0; cc < 8; ++cc)
      sum += *(const f32x4*)(rb + (g * 8 + cc) * 68 + c * 4);
#pragma unroll
    for (int i = 0; i < 4; ++i) {
      float v = sum[i];
      v += __shfl_xor(v, 16, 64); v += __shfl_xor(v, 32, 64);
      sum[i] = v * 0.03125f;
    }
    if (g == 0) *(f32x4*)(mb + 64 * h + c * 4) = sum;
  }

  // ---------------- head: out = Wp * pooled + bp (f32) ----------------
  float p0 = mb[lane], p1 = mb[64 + lane];
  float po[5];
#pragma unroll
  for (int o = 0; o < 5; ++o)
    po[o] = p0 * Wp[o * 128 + lane] + p1 * Wp[o * 128 + 64 + lane];
#pragma unroll
  for (int o = 0; o < 5; ++o) {
    float v = po[o];
    v += __shfl_xor(v, 1, 64);  v += __shfl_xor(v, 2, 64);
    v += __shfl_xor(v, 4, 64);  v += __shfl_xor(v, 8, 64);
    v += __shfl_xor(v, 16, 64); v += __shfl_xor(v, 32, 64);
    po[o] = v;
  }
  if (lane == 0) {
#pragma unroll
    for (int o = 0; o < 5; ++o) out[graph * 5 + o] = po[o] + bp[o];
  }
}

extern "C" void kernel_launch(void* const* d_in, const int* in_sizes, int n_in,
                              void* d_out, int out_size, void* d_ws, size_t ws_size,
                              hipStream_t stream)
{
  const float* obs = (const float*)d_in[0];
  // d_in[1]=src, d_in[2]=dst: fully-connected per-graph -> segment mean; unused.
  const float* W1l = (const float*)d_in[3];
  const float* b1  = (const float*)d_in[4];
  const float* W1r = (const float*)d_in[5];
  const float* W2l = (const float*)d_in[6];
  const float* b2  = (const float*)d_in[7];
  const float* W2r = (const float*)d_in[8];
  const float* W3l = (const float*)d_in[9];
  const float* b3  = (const float*)d_in[10];
  const float* W3r = (const float*)d_in[11];
  const float* Wp  = (const float*)d_in[12];
  const float* bp  = (const float*)d_in[13];
  unsigned short* wpack = (unsigned short*)d_ws;   // needs 104 KB of d_ws
  float* out = (float*)d_out;

  gnn_prep<<<208, 256, 0, stream>>>(W1l, W1r, W2l, W2r, W3l, W3r, wpack);
  gnn_fused<<<256, 512, 0, stream>>>(obs, b1, b2, b3, Wp, bp, wpack, out);
}